// Round 3
// baseline (305.315 us; speedup 1.0000x reference)
//
#include <hip/hip_runtime.h>

constexpr int NN  = 20000;   // nodes
constexpr int NE  = 160000;  // edges (= 625*256)
constexpr int CAP = 32;      // per-node bucket capacity (deg ~ Poisson(8), max ~21)
constexpr int TN  = 32;      // node tile per block (D2 nodeP1 only)
constexpr int NBM = 16;      // blocks in MLP kernel

// ---- agent-scope (cross-XCD safe) scalar access --------------------------
__device__ inline void gstore(float* p, float v) {
    __hip_atomic_store(p, v, __ATOMIC_RELAXED, __HIP_MEMORY_SCOPE_AGENT);
}
__device__ inline float gload(const float* p) {
    return __hip_atomic_load(p, __ATOMIC_RELAXED, __HIP_MEMORY_SCOPE_AGENT);
}

// inter-block barrier: monotonic counter, arrive then (optionally) spin
__device__ inline void mbarrier(int* ctr, int target, bool wait) {
    __syncthreads();
    if (threadIdx.x == 0) {
        __threadfence();
        __hip_atomic_fetch_add(ctr, 1, __ATOMIC_ACQ_REL, __HIP_MEMORY_SCOPE_AGENT);
        if (wait)
            while (__hip_atomic_load(ctr, __ATOMIC_ACQUIRE, __HIP_MEMORY_SCOPE_AGENT) < target) {}
    }
    __syncthreads();
}

// ---------------------------------------------------------------------------
// Full-W staging (D2 only). Rows s<8 = We, s==8 = be, s==9 = root.
// Layout Wlds[f * (10*FO2) + s*FO2 + o].
// ---------------------------------------------------------------------------
template<int FI, int FO2>
__device__ void stage_W(float* Wlds, const float* __restrict__ We,
                        const float* __restrict__ be, const float* __restrict__ root)
{
    constexpr int PW = 10 * FO2, C4 = PW / 4, O4 = FO2 / 4;
    for (int t = threadIdx.x; t < FI * C4; t += 256) {
        const int f = t / C4, r = t % C4, s = r / O4, oq = r % O4;
        const float4* src;
        if (s < 8)       src = (const float4*)(We + (size_t)s * FI * FO2 + f * FO2 + oq * 4);
        else if (s == 8) src = (const float4*)(be + f * FO2 + oq * 4);
        else             src = (const float4*)(root + f * FO2 + oq * 4);
        ((float4*)Wlds)[t] = *src;
    }
}

// Half-W staging: columns cc in [c0, c0+CH). Wh4[f*CH + (cc-c0)].
template<int FI, int FO2, int CH>
__device__ void stage_half(float* Wh, const float* __restrict__ We,
                           const float* __restrict__ be, const float* __restrict__ root,
                           int c0)
{
    constexpr int O4 = FO2 / 4;
    for (int t = threadIdx.x; t < FI * CH; t += 256) {
        const int f = t / CH, ccp = t % CH, cc = c0 + ccp;
        const int s = cc / O4, oq = cc % O4;
        const float4* src;
        if (s < 8)       src = (const float4*)(We + (size_t)s * FI * FO2 + f * FO2 + oq * 4);
        else if (s == 8) src = (const float4*)(be + f * FO2 + oq * 4);
        else             src = (const float4*)(root + f * FO2 + oq * 4);
        ((float4*)Wh)[t] = *src;
    }
}

// ---------------------------------------------------------------------------
// Full-width GEMM (D2 only): TN-node h-tile (stride FI+4) x Wlds -> Pout.
// ---------------------------------------------------------------------------
template<int FI, int FO2>
__device__ void gemm_tile(const float* htile, const float* Wlds,
                          const float* __restrict__ bias, float* __restrict__ Pout, int n0)
{
    constexpr int PW = 10 * FO2, C4 = PW / 4, O4 = FO2 / 4;
    constexpr int TPN = 256 / TN;            // 8
    const int nl = threadIdx.x / TPN;
    const int lane = threadIdx.x % TPN;
    const int n = n0 + nl;
    if (n >= NN) return;
    const float*  hr = &htile[nl * (FI + 4)];
    const float4* W4 = (const float4*)Wlds;
    float4* Pr = (float4*)(Pout + (size_t)n * PW);
    for (int cc = lane; cc < C4; cc += TPN) {
        float4 a = {0.f, 0.f, 0.f, 0.f};
        #pragma unroll
        for (int f = 0; f < FI; f++) {
            const float  hf = hr[f];
            const float4 w  = W4[f * C4 + cc];
            a.x = fmaf(hf, w.x, a.x); a.y = fmaf(hf, w.y, a.y);
            a.z = fmaf(hf, w.z, a.z); a.w = fmaf(hf, w.w, a.w);
        }
        if (cc >= 9 * O4) {
            const float4 b4 = ((const float4*)bias)[cc - 9 * O4];
            a.x += b4.x; a.y += b4.y; a.z += b4.z; a.w += b4.w;
        }
        Pr[cc] = a;
    }
}

// Half-width GEMM: columns cc in [c0, c0+CH), W from Wh half-stage.
template<int FI, int FO2, int TN2>
__device__ void gemm_half(const float* htile, const float* Wh,
                          const float* __restrict__ bias, float* __restrict__ Pout,
                          int n0, int c0)
{
    constexpr int PW = 10 * FO2, C4 = PW / 4, CH = C4 / 2, O4 = FO2 / 4;
    constexpr int TPN = 256 / TN2;           // 32
    constexpr int HS  = FI + 4;
    const int nl = threadIdx.x / TPN, lane = threadIdx.x % TPN;
    const int n = n0 + nl;
    const float*  hr = &htile[nl * HS];
    const float4* W4 = (const float4*)Wh;
    float4* Pr = (float4*)(Pout + (size_t)n * PW);
    for (int ccp = lane; ccp < CH; ccp += TPN) {
        const int cc = c0 + ccp;
        float4 a = {0.f, 0.f, 0.f, 0.f};
        #pragma unroll
        for (int f = 0; f < FI; f++) {
            const float  hf = hr[f];
            const float4 w  = W4[f * CH + ccp];
            a.x = fmaf(hf, w.x, a.x); a.y = fmaf(hf, w.y, a.y);
            a.z = fmaf(hf, w.z, a.z); a.w = fmaf(hf, w.w, a.w);
        }
        if (cc >= 9 * O4) {
            const float4 b4 = ((const float4*)bias)[cc - 9 * O4];
            a.x += b4.x; a.y += b4.y; a.z += b4.z; a.w += b4.w;
        }
        Pr[cc] = a;
    }
}

// Shared 9-segment edge accumulation: acc += Pr[8FO] + sum_s e_s * Pr[sFO].
template<int FO>
__device__ inline void edge_fma(float4& acc, const float* __restrict__ Pr,
                                const float* __restrict__ eq)
{
    const float4 e0 = ((const float4*)eq)[0];
    const float4 e1 = ((const float4*)eq)[1];
    float4 a = *(const float4*)(Pr + 8 * FO);
    float4 w;
    w = *(const float4*)(Pr + 0 * FO);
    a.x = fmaf(e0.x, w.x, a.x); a.y = fmaf(e0.x, w.y, a.y);
    a.z = fmaf(e0.x, w.z, a.z); a.w = fmaf(e0.x, w.w, a.w);
    w = *(const float4*)(Pr + 1 * FO);
    a.x = fmaf(e0.y, w.x, a.x); a.y = fmaf(e0.y, w.y, a.y);
    a.z = fmaf(e0.y, w.z, a.z); a.w = fmaf(e0.y, w.w, a.w);
    w = *(const float4*)(Pr + 2 * FO);
    a.x = fmaf(e0.z, w.x, a.x); a.y = fmaf(e0.z, w.y, a.y);
    a.z = fmaf(e0.z, w.z, a.z); a.w = fmaf(e0.z, w.w, a.w);
    w = *(const float4*)(Pr + 3 * FO);
    a.x = fmaf(e0.w, w.x, a.x); a.y = fmaf(e0.w, w.y, a.y);
    a.z = fmaf(e0.w, w.z, a.z); a.w = fmaf(e0.w, w.w, a.w);
    w = *(const float4*)(Pr + 4 * FO);
    a.x = fmaf(e1.x, w.x, a.x); a.y = fmaf(e1.x, w.y, a.y);
    a.z = fmaf(e1.x, w.z, a.z); a.w = fmaf(e1.x, w.w, a.w);
    w = *(const float4*)(Pr + 5 * FO);
    a.x = fmaf(e1.y, w.x, a.x); a.y = fmaf(e1.y, w.y, a.y);
    a.z = fmaf(e1.y, w.z, a.z); a.w = fmaf(e1.y, w.w, a.w);
    w = *(const float4*)(Pr + 6 * FO);
    a.x = fmaf(e1.z, w.x, a.x); a.y = fmaf(e1.z, w.y, a.y);
    a.z = fmaf(e1.z, w.z, a.z); a.w = fmaf(e1.z, w.w, a.w);
    w = *(const float4*)(Pr + 7 * FO);
    a.x = fmaf(e1.w, w.x, a.x); a.y = fmaf(e1.w, w.y, a.y);
    a.z = fmaf(e1.w, w.z, a.z); a.w = fmaf(e1.w, w.w, a.w);
    acc.x += a.x; acc.y += a.y; acc.z += a.z; acc.w += a.w;
}

// ---------------------------------------------------------------------------
// D2: blocks [0,625) fill edge buckets; blocks [625,1250) nodeP layer-1 tiles.
// ---------------------------------------------------------------------------
__global__ __launch_bounds__(256)
void fill_nodeP1_kernel(const int* __restrict__ eidx, const float* __restrict__ e,
                        const float* __restrict__ x,
                        const float* __restrict__ We1, const float* __restrict__ be1,
                        const float* __restrict__ root1, const float* __restrict__ b1,
                        int* __restrict__ cnt, int* __restrict__ adjsrc,
                        float* __restrict__ esort, float* __restrict__ Pa)
{
    __shared__ float smem[16 * 400 + TN * 20];     // 6400 + 640 floats
    const int b = blockIdx.x, tid = threadIdx.x;
    if (b < 625) {
        const int eid = b * 256 + tid;             // NE == 625*256
        const int2 st = ((const int2*)eidx)[eid];
        const int q = atomicAdd(&cnt[st.y], 1);
        if (q < CAP) {
            const int slot = st.y * CAP + q;
            adjsrc[slot] = st.x;
            const float4* e4 = (const float4*)(e + (size_t)eid * 8);
            float4* o4 = (float4*)(esort + (size_t)slot * 8);
            o4[0] = e4[0];
            o4[1] = e4[1];
        }
    } else {
        float* Wlds  = smem;
        float* htile = smem + 6400;
        stage_W<16, 40>(Wlds, We1, be1, root1);
        const int n0 = (b - 625) * TN;
        for (int t = tid; t < TN * 4; t += 256) {  // 16 floats = 4 quads/node
            const int nl = t / 4, fq = t % 4;
            const int n = n0 + nl;
            float4 v = {0.f, 0.f, 0.f, 0.f};
            if (n < NN) v = ((const float4*)(x + (size_t)n * 16))[fq];
            *((float4*)&htile[nl * 20 + fq * 4]) = v;
        }
        __syncthreads();
        gemm_tile<16, 40>(htile, Wlds, b1, Pa, n0);
    }
}

// ---------------------------------------------------------------------------
// D3/D4 v2: fused gather + nodeP at high occupancy.
// TN2=8 nodes/block (grid 2500), J-way edge split per (node, oq) with LDS
// ds_add_f32 combine, two-pass W staging (half the columns at a time) so
// LDS stays ~20 KB; __launch_bounds__(256,6) targets 24 waves/CU.
// ---------------------------------------------------------------------------
template<int FO, int FO2, int TN2, int J>
__global__ __launch_bounds__(256, 6)
void gather_nodeP2_kernel(const float* __restrict__ Pin, const int* __restrict__ cnt,
                          const int* __restrict__ adjsrc, const float* __restrict__ esort,
                          const float* __restrict__ We2, const float* __restrict__ be2,
                          const float* __restrict__ root2, const float* __restrict__ b2,
                          float* __restrict__ Pout)
{
    constexpr int PW1 = 10 * FO;
    constexpr int PW2 = 10 * FO2;
    constexpr int C4  = PW2 / 4;
    constexpr int CH  = C4 / 2;
    constexpr int OQ  = FO / 4;
    constexpr int HS  = FO + 4;
    __shared__ float Wh[FO * CH * 4];
    __shared__ float htile[TN2 * HS];
    const int tid = threadIdx.x;
    const int n0  = blockIdx.x * TN2;       // grid 2500 * 8 == NN exactly

    // stage W columns [0,CH) + init htile with root+bias segment
    stage_half<FO, FO2, CH>(Wh, We2, be2, root2, 0);
    for (int t = tid; t < TN2 * OQ; t += 256) {
        const int nl = t / OQ, oq = t % OQ;
        *(float4*)&htile[nl * HS + oq * 4] =
            *(const float4*)(Pin + (size_t)(n0 + nl) * PW1 + 9 * FO + oq * 4);
    }
    __syncthreads();

    // edge phase: (node, oq, jh) items; local acc, one LDS-atomic combine
    for (int T = tid; T < TN2 * OQ * J; T += 256) {
        const int nl = T / (OQ * J), r = T % (OQ * J), oq = r / J, jh = r % J;
        const int n = n0 + nl;
        const int d = min(cnt[n], CAP);
        if (jh >= d) continue;
        float4 acc = {0.f, 0.f, 0.f, 0.f};
        const int*   ab    = adjsrc + n * CAP;
        const float* ebase = esort + (size_t)n * CAP * 8;
        for (int j = jh; j < d; j += J) {
            const int src = ab[j];
            edge_fma<FO>(acc, Pin + (size_t)src * PW1 + oq * 4, ebase + j * 8);
        }
        float* hp = &htile[nl * HS + oq * 4];
        atomicAdd(hp + 0, acc.x);
        atomicAdd(hp + 1, acc.y);
        atomicAdd(hp + 2, acc.z);
        atomicAdd(hp + 3, acc.w);
    }
    __syncthreads();

    // relu
    for (int t = tid; t < TN2 * OQ; t += 256) {
        float4* p = (float4*)&htile[(t / OQ) * HS + (t % OQ) * 4];
        float4 v = *p;
        v.x = fmaxf(v.x, 0.f); v.y = fmaxf(v.y, 0.f);
        v.z = fmaxf(v.z, 0.f); v.w = fmaxf(v.w, 0.f);
        *p = v;
    }
    __syncthreads();

    gemm_half<FO, FO2, TN2>(htile, Wh, b2, Pout, n0, 0);
    __syncthreads();
    stage_half<FO, FO2, CH>(Wh, We2, be2, root2, CH);
    __syncthreads();
    gemm_half<FO, FO2, TN2>(htile, Wh, b2, Pout, n0, CH);
}

// ---------------------------------------------------------------------------
// D5 v2: gather layer 3 + colsum -> g, same high-occupancy structure.
// ---------------------------------------------------------------------------
template<int TN2, int J>
__global__ __launch_bounds__(256, 6)
void gather_colsum2_kernel(const float* __restrict__ Pin, const int* __restrict__ cnt,
                           const int* __restrict__ adjsrc, const float* __restrict__ esort,
                           float* __restrict__ g)
{
    constexpr int FO = 24, PW1 = 240, OQ = 6, HS = 28;
    __shared__ float htile[TN2 * HS];
    __shared__ float gl[FO];
    const int tid = threadIdx.x;
    const int n0  = blockIdx.x * TN2;

    if (tid < FO) gl[tid] = 0.f;
    for (int t = tid; t < TN2 * OQ; t += 256) {
        const int nl = t / OQ, oq = t % OQ;
        *(float4*)&htile[nl * HS + oq * 4] =
            *(const float4*)(Pin + (size_t)(n0 + nl) * PW1 + 9 * FO + oq * 4);
    }
    __syncthreads();

    for (int T = tid; T < TN2 * OQ * J; T += 256) {
        const int nl = T / (OQ * J), r = T % (OQ * J), oq = r / J, jh = r % J;
        const int n = n0 + nl;
        const int d = min(cnt[n], CAP);
        if (jh >= d) continue;
        float4 acc = {0.f, 0.f, 0.f, 0.f};
        const int*   ab    = adjsrc + n * CAP;
        const float* ebase = esort + (size_t)n * CAP * 8;
        for (int j = jh; j < d; j += J) {
            const int src = ab[j];
            edge_fma<FO>(acc, Pin + (size_t)src * PW1 + oq * 4, ebase + j * 8);
        }
        float* hp = &htile[nl * HS + oq * 4];
        atomicAdd(hp + 0, acc.x);
        atomicAdd(hp + 1, acc.y);
        atomicAdd(hp + 2, acc.z);
        atomicAdd(hp + 3, acc.w);
    }
    __syncthreads();

    // relu + column sum into gl
    for (int t = tid; t < TN2 * OQ; t += 256) {
        const int nl = t / OQ, oq = t % OQ;
        const float4 v = *(const float4*)&htile[nl * HS + oq * 4];
        atomicAdd(&gl[oq * 4 + 0], fmaxf(v.x, 0.f));
        atomicAdd(&gl[oq * 4 + 1], fmaxf(v.y, 0.f));
        atomicAdd(&gl[oq * 4 + 2], fmaxf(v.z, 0.f));
        atomicAdd(&gl[oq * 4 + 3], fmaxf(v.w, 0.f));
    }
    __syncthreads();
    if (tid < FO) unsafeAtomicAdd(&g[tid], gl[tid]);
}

// ---------------------------------------------------------------------------
// D6: MLP head, 16 blocks, 2 inter-block barriers.
// L1/L2 redundant per block; L3/L4 partitioned; L5+L6 in block 0.
// ---------------------------------------------------------------------------
__global__ __launch_bounds__(256)
void mlp_kernel(const float* __restrict__ g, int* __restrict__ ctr,
                const float* __restrict__ Wd1, const float* __restrict__ bd1,
                const float* __restrict__ Wd2, const float* __restrict__ bd2,
                const float* __restrict__ Wd3, const float* __restrict__ bd3,
                const float* __restrict__ Wd4, const float* __restrict__ bd4,
                const float* __restrict__ Wd5, const float* __restrict__ bd5,
                const float* __restrict__ Wd6, const float* __restrict__ bd6,
                float* __restrict__ m3, float* __restrict__ m4,
                float* __restrict__ out)
{
    __shared__ float v0[768];     // layer input
    __shared__ float v1[96];      // L1 output
    __shared__ float red[256];
    const int tid = threadIdx.x, b = blockIdx.x;

    // ---- L1: 24 -> 96, redundant per block ----
    if (tid < 24) v0[tid] = g[tid];          // g from previous dispatch: coherent
    __syncthreads();
    if (tid < 96) {
        float a = bd1[tid];
        #pragma unroll
        for (int i = 0; i < 24; i++) a = fmaf(v0[i], Wd1[i * 96 + tid], a);
        v1[tid] = fmaxf(a, 0.f);
    }
    __syncthreads();

    // ---- L2: 96 -> 256, redundant per block (one output per thread) ----
    {
        float a = bd2[tid];
        #pragma unroll
        for (int i = 0; i < 96; i++) a = fmaf(v1[i], Wd2[i * 256 + tid], a);
        red[tid] = fmaxf(a, 0.f);
    }
    __syncthreads();
    v0[tid] = red[tid];                       // L2 output -> v0[0..255]
    __syncthreads();

    // ---- L3: 256 -> 768, partitioned (48 outputs/block; 4 kg x K=64) ----
    if (tid < 192) {
        const int o = b * 48 + (tid % 48), kg = tid / 48;
        float a = 0.f;
        #pragma unroll 8
        for (int i = kg * 64; i < kg * 64 + 64; i++)
            a = fmaf(v0[i], Wd3[(size_t)i * 768 + o], a);
        red[tid] = a;
    }
    __syncthreads();
    if (tid < 48) {
        float s = bd3[b * 48 + tid] + red[tid] + red[48 + tid] + red[96 + tid] + red[144 + tid];
        gstore(&m3[b * 48 + tid], fmaxf(s, 0.f));
    }
    mbarrier(ctr, 1 * NBM, true);

    // ---- L4: 768 -> 512, partitioned (32 outputs/block; 8 kg x K=96) ----
    for (int i = tid; i < 768; i += 256) v0[i] = gload(&m3[i]);
    __syncthreads();
    {
        const int o = b * 32 + (tid & 31), kg = tid >> 5;
        float a = 0.f;
        #pragma unroll 8
        for (int i = kg * 96; i < kg * 96 + 96; i++)
            a = fmaf(v0[i], Wd4[(size_t)i * 512 + o], a);
        red[tid] = a;
    }
    __syncthreads();
    if (tid < 32) {
        float s = bd4[b * 32 + tid];
        #pragma unroll
        for (int k = 0; k < 8; k++) s += red[k * 32 + tid];
        gstore(&m4[b * 32 + tid], fmaxf(s, 0.f));
    }
    mbarrier(ctr, 2 * NBM, b == 0);          // only block 0 must wait

    // ---- L5+L6 in block 0: 512 -> 64 -> 1 ----
    if (b == 0) {
        for (int i = tid; i < 512; i += 256) v0[i] = gload(&m4[i]);
        __syncthreads();
        {
            const int o = tid & 63, kg = tid >> 6;   // 4 kg x K=128
            float a = 0.f;
            #pragma unroll 8
            for (int i = kg * 128; i < kg * 128 + 128; i++)
                a = fmaf(v0[i], Wd5[(size_t)i * 64 + o], a);
            red[tid] = a;
        }
        __syncthreads();
        if (tid < 64) {
            float s = bd5[tid] + red[tid] + red[64 + tid] + red[128 + tid] + red[192 + tid];
            float v = fmaxf(s, 0.f) * Wd6[tid];
            #pragma unroll
            for (int off = 32; off > 0; off >>= 1)
                v += __shfl_down(v, off, 64);
            if (tid == 0) out[0] = v + bd6[0];
        }
    }
}

// ---------------------------------------------------------------------------
extern "C" void kernel_launch(void* const* d_in, const int* in_sizes, int n_in,
                              void* d_out, int out_size, void* d_ws, size_t ws_size,
                              hipStream_t stream)
{
    const float* x     = (const float*)d_in[0];
    const int*   eidx  = (const int*)  d_in[1];
    const float* e     = (const float*)d_in[2];
    const float* We1   = (const float*)d_in[3];  const float* be1 = (const float*)d_in[4];
    const float* root1 = (const float*)d_in[5];  const float* b1  = (const float*)d_in[6];
    const float* We2   = (const float*)d_in[7];  const float* be2 = (const float*)d_in[8];
    const float* root2 = (const float*)d_in[9];  const float* b2  = (const float*)d_in[10];
    const float* We3   = (const float*)d_in[11]; const float* be3 = (const float*)d_in[12];
    const float* root3 = (const float*)d_in[13]; const float* b3  = (const float*)d_in[14];
    const float* Wd1 = (const float*)d_in[15]; const float* bd1 = (const float*)d_in[16];
    const float* Wd2 = (const float*)d_in[17]; const float* bd2 = (const float*)d_in[18];
    const float* Wd3 = (const float*)d_in[19]; const float* bd3 = (const float*)d_in[20];
    const float* Wd4 = (const float*)d_in[21]; const float* bd4 = (const float*)d_in[22];
    const float* Wd5 = (const float*)d_in[23]; const float* bd5 = (const float*)d_in[24];
    const float* Wd6 = (const float*)d_in[25]; const float* bd6 = (const float*)d_in[26];

    // ---- workspace layout (4-byte units) ----
    int*   wi     = (int*)d_ws;
    int*   cnt    = wi;                        //       0 ..  20000
    float* g      = (float*)d_ws + 20000;      //   20000 ..  20024
    int*   mctr   = wi + 20032;                //   20032 (own 64B line)
    float* m3     = (float*)d_ws + 20064;      //   768
    float* m4     = m3 + 768;                  //   512  (ends 21344 < 21760)
    int*   adjsrc = wi + 21760;                //   20000*32 = 640,000
    float* wf     = (float*)d_ws;
    float* esort  = wf + 661760;               //   20000*32*8 = 5,120,000
    float* Pa     = wf + 5781760;              //   20000*400 = 8,000,000 max
    float* Pb     = wf + 13781760;             //   20000*240 = 4,800,000
    // total ~18.58M floats ~= 74 MB

    // D1: zero cnt + g + mctr (+ m vectors, harmless)
    hipMemsetAsync(d_ws, 0, (size_t)21760 * sizeof(int), stream);

    // D2: edge buckets + nodeP layer 1 (x -> Pa, width 400)
    fill_nodeP1_kernel<<<1250, 256, 0, stream>>>(eidx, e, x, We1, be1, root1, b1,
                                                 cnt, adjsrc, esort, Pa);

    // D3: gather L1 (h1 in LDS) + nodeP L2 -> Pb (width 240); 2500 blocks
    gather_nodeP2_kernel<40, 24, 8, 4><<<2500, 256, 0, stream>>>(Pa, cnt, adjsrc, esort,
                                                                 We2, be2, root2, b2, Pb);

    // D4: gather L2 (h2 in LDS) + nodeP L3 -> Pa (width 240); 2500 blocks
    gather_nodeP2_kernel<24, 24, 8, 6><<<2500, 256, 0, stream>>>(Pb, cnt, adjsrc, esort,
                                                                 We3, be3, root3, b3, Pa);

    // D5: gather L3 + colsum -> g; 2500 blocks
    gather_colsum2_kernel<8, 6><<<2500, 256, 0, stream>>>(Pa, cnt, adjsrc, esort, g);

    // D6: MLP head (16 blocks, 2 internal barriers)
    mlp_kernel<<<NBM, 256, 0, stream>>>(g, mctr,
                                        Wd1, bd1, Wd2, bd2, Wd3, bd3,
                                        Wd4, bd4, Wd5, bd5, Wd6, bd6,
                                        m3, m4, (float*)d_out);
}

// Round 4
// 281.987 us; speedup vs baseline: 1.0827x; 1.0827x over previous
//
#include <hip/hip_runtime.h>

constexpr int NN  = 20000;   // nodes
constexpr int NE  = 160000;  // edges (= 625*256)
constexpr int CAP = 32;      // per-node out-edge bucket capacity (deg ~ Poisson(8))
constexpr int TN  = 32;      // node tile per block (GEMM kernels)
constexpr int NBM = 16;      // blocks in MLP kernel

// ---- agent-scope (cross-XCD safe) scalar access --------------------------
__device__ inline void gstore(float* p, float v) {
    __hip_atomic_store(p, v, __ATOMIC_RELAXED, __HIP_MEMORY_SCOPE_AGENT);
}
__device__ inline float gload(const float* p) {
    return __hip_atomic_load(p, __ATOMIC_RELAXED, __HIP_MEMORY_SCOPE_AGENT);
}

// inter-block barrier: monotonic counter, arrive then (optionally) spin
__device__ inline void mbarrier(int* ctr, int target, bool wait) {
    __syncthreads();
    if (threadIdx.x == 0) {
        __threadfence();
        __hip_atomic_fetch_add(ctr, 1, __ATOMIC_ACQ_REL, __HIP_MEMORY_SCOPE_AGENT);
        if (wait)
            while (__hip_atomic_load(ctr, __ATOMIC_ACQUIRE, __HIP_MEMORY_SCOPE_AGENT) < target) {}
    }
    __syncthreads();
}

// ---------------------------------------------------------------------------
// Stage W into LDS: rows s<8 = We, s==8 = be, s==9 = root.
// Layout Wlds[f * (10*FO2) + s*FO2 + o].
// ---------------------------------------------------------------------------
template<int FI, int FO2>
__device__ void stage_W(float* Wlds, const float* __restrict__ We,
                        const float* __restrict__ be, const float* __restrict__ root)
{
    constexpr int PW = 10 * FO2, C4 = PW / 4, O4 = FO2 / 4;
    for (int t = threadIdx.x; t < FI * C4; t += 256) {
        const int f = t / C4, r = t % C4, s = r / O4, oq = r % O4;
        const float4* src;
        if (s < 8)       src = (const float4*)(We + (size_t)s * FI * FO2 + f * FO2 + oq * 4);
        else if (s == 8) src = (const float4*)(be + f * FO2 + oq * 4);
        else             src = (const float4*)(root + f * FO2 + oq * 4);
        ((float4*)Wlds)[t] = *src;
    }
}

// ---------------------------------------------------------------------------
// GEMM a TN-node h-tile (LDS, stride FI+4) against Wlds -> Pout rows.
// Root block (s==9) gets +bias. 8 threads per node.
// ---------------------------------------------------------------------------
template<int FI, int FO2>
__device__ void gemm_tile(const float* htile, const float* Wlds,
                          const float* __restrict__ bias, float* __restrict__ Pout, int n0)
{
    constexpr int PW = 10 * FO2, C4 = PW / 4, O4 = FO2 / 4;
    constexpr int TPN = 256 / TN;            // 8
    const int nl = threadIdx.x / TPN;
    const int lane = threadIdx.x % TPN;
    const int n = n0 + nl;
    if (n >= NN) return;
    const float*  hr = &htile[nl * (FI + 4)];
    const float4* W4 = (const float4*)Wlds;
    float4* Pr = (float4*)(Pout + (size_t)n * PW);
    for (int cc = lane; cc < C4; cc += TPN) {
        float4 a = {0.f, 0.f, 0.f, 0.f};
        #pragma unroll
        for (int f = 0; f < FI; f++) {
            const float  hf = hr[f];
            const float4 w  = W4[f * C4 + cc];
            a.x = fmaf(hf, w.x, a.x); a.y = fmaf(hf, w.y, a.y);
            a.z = fmaf(hf, w.z, a.z); a.w = fmaf(hf, w.w, a.w);
        }
        if (cc >= 9 * O4) {
            const float4 b4 = ((const float4*)bias)[cc - 9 * O4];
            a.x += b4.x; a.y += b4.y; a.z += b4.z; a.w += b4.w;
        }
        Pr[cc] = a;
    }
}

// ---------------------------------------------------------------------------
// D2: blocks [0,625) bucket edges BY SOURCE; blocks [625,1250) nodeP L1 tiles.
// ---------------------------------------------------------------------------
__global__ __launch_bounds__(256)
void fill_nodeP1_kernel(const int* __restrict__ eidx, const float* __restrict__ x,
                        const float* __restrict__ We1, const float* __restrict__ be1,
                        const float* __restrict__ root1, const float* __restrict__ b1,
                        int* __restrict__ cnt_s, int* __restrict__ se_eid,
                        int* __restrict__ se_tgt, float* __restrict__ Pa)
{
    __shared__ float smem[16 * 400 + TN * 20];     // 6400 + 640 floats
    const int b = blockIdx.x, tid = threadIdx.x;
    if (b < 625) {
        const int eid = b * 256 + tid;             // NE == 625*256
        const int2 st = ((const int2*)eidx)[eid];
        const int q = atomicAdd(&cnt_s[st.x], 1);
        if (q < CAP) {
            se_eid[st.x * CAP + q] = eid;
            se_tgt[st.x * CAP + q] = st.y;
        }
    } else {
        float* Wlds  = smem;
        float* htile = smem + 6400;
        stage_W<16, 40>(Wlds, We1, be1, root1);
        const int n0 = (b - 625) * TN;
        for (int t = tid; t < TN * 4; t += 256) {  // 16 floats = 4 quads/node
            const int nl = t / 4, fq = t % 4;
            const int n = n0 + nl;
            float4 v = {0.f, 0.f, 0.f, 0.f};
            if (n < NN) v = ((const float4*)(x + (size_t)n * 16))[fq];
            *((float4*)&htile[nl * 20 + fq * 4]) = v;
        }
        __syncthreads();
        gemm_tile<16, 40>(htile, Wlds, b1, Pa, n0);
    }
}

// ---------------------------------------------------------------------------
// PUSH: iterate by source. Lane o (< FO) keeps the 9 P-segments of its
// channel in registers (row read ONCE, sequential); per out-edge compute
// msg_o = P[8]+Σ_s e_s P[s] (9 fma) and scatter-add into hagg[tgt*FO+o].
// GSZ lanes per src (64 for FO=40, 32 for FO=24); 256/GSZ srcs per block.
// ---------------------------------------------------------------------------
template<int FO, int PW1, int GSZ>
__global__ __launch_bounds__(256)
void push_kernel(const float* __restrict__ Pin, const int* __restrict__ cnt_s,
                 const int* __restrict__ se_eid, const int* __restrict__ se_tgt,
                 const float* __restrict__ e, float* __restrict__ hagg)
{
    constexpr int SPB = 256 / GSZ;
    const int tid = threadIdx.x;
    const int o   = tid % GSZ;               // channel (active if < FO)
    const int n   = blockIdx.x * SPB + tid / GSZ;   // grid*SPB == NN exactly

    float p[9];
    if (o < FO) {
        #pragma unroll
        for (int s = 0; s < 9; s++)
            p[s] = Pin[(size_t)n * PW1 + s * FO + o];
    }
    const int d = min(cnt_s[n], CAP);
    const int* eb = se_eid + n * CAP;
    const int* tb = se_tgt + n * CAP;
    for (int j = 0; j < d; j++) {
        const int eid = eb[j];
        const int tgt = tb[j];
        const float4 e0 = *(const float4*)(e + (size_t)eid * 8);
        const float4 e1 = *(const float4*)(e + (size_t)eid * 8 + 4);
        if (o < FO) {
            float m = p[8];
            m = fmaf(e0.x, p[0], m); m = fmaf(e0.y, p[1], m);
            m = fmaf(e0.z, p[2], m); m = fmaf(e0.w, p[3], m);
            m = fmaf(e1.x, p[4], m); m = fmaf(e1.y, p[5], m);
            m = fmaf(e1.z, p[6], m); m = fmaf(e1.w, p[7], m);
            unsafeAtomicAdd(&hagg[(size_t)tgt * FO + o], m);
        }
    }
}

// ---------------------------------------------------------------------------
// hgemm: h = relu(hagg + Pin seg9) (all sequential reads), then nodeP GEMM.
// ---------------------------------------------------------------------------
template<int FI, int FO2>
__global__ __launch_bounds__(256)
void hgemm_kernel(const float* __restrict__ hagg, const float* __restrict__ Pin,
                  const float* __restrict__ We, const float* __restrict__ be,
                  const float* __restrict__ root, const float* __restrict__ bias,
                  float* __restrict__ Pout)
{
    constexpr int PW_IN = 10 * FI, HS = FI + 4, OQ = FI / 4;
    __shared__ float smem[FI * 10 * FO2 + TN * HS];
    float* Wlds  = smem;
    float* htile = smem + FI * 10 * FO2;
    stage_W<FI, FO2>(Wlds, We, be, root);
    const int n0 = blockIdx.x * TN;
    for (int t = threadIdx.x; t < TN * OQ; t += 256) {
        const int nl = t / OQ, oq = t % OQ;
        const int n = n0 + nl;
        const float4 hv = *(const float4*)(hagg + (size_t)n * FI + oq * 4);
        const float4 rv = *(const float4*)(Pin + (size_t)n * PW_IN + 9 * FI + oq * 4);
        float4 r = {fmaxf(hv.x + rv.x, 0.f), fmaxf(hv.y + rv.y, 0.f),
                    fmaxf(hv.z + rv.z, 0.f), fmaxf(hv.w + rv.w, 0.f)};
        *(float4*)&htile[nl * HS + oq * 4] = r;
    }
    __syncthreads();
    gemm_tile<FI, FO2>(htile, Wlds, bias, Pout, n0);
}

// ---------------------------------------------------------------------------
// D5b: g[o] = sum_n relu(hagg3[n,o] + Pin[n, seg9 + o])   (24-wide)
// ---------------------------------------------------------------------------
__global__ __launch_bounds__(256)
void colsum_kernel(const float* __restrict__ hagg3, const float* __restrict__ Pin,
                   float* __restrict__ g)
{
    __shared__ float gl[24];
    const int tid = threadIdx.x;
    if (tid < 24) gl[tid] = 0.f;
    __syncthreads();
    for (int i = blockIdx.x * 256 + tid; i < NN * 24; i += gridDim.x * 256) {
        const int n = i / 24, o = i - n * 24;
        const float v = fmaxf(hagg3[i] + Pin[(size_t)n * 240 + 216 + o], 0.f);
        atomicAdd(&gl[o], v);
    }
    __syncthreads();
    if (tid < 24) unsafeAtomicAdd(&g[tid], gl[tid]);
}

// ---------------------------------------------------------------------------
// D6: MLP head, 16 blocks, 2 inter-block barriers.
// L1/L2 redundant per block; L3/L4 partitioned; L5+L6 in block 0.
// ---------------------------------------------------------------------------
__global__ __launch_bounds__(256)
void mlp_kernel(const float* __restrict__ g, int* __restrict__ ctr,
                const float* __restrict__ Wd1, const float* __restrict__ bd1,
                const float* __restrict__ Wd2, const float* __restrict__ bd2,
                const float* __restrict__ Wd3, const float* __restrict__ bd3,
                const float* __restrict__ Wd4, const float* __restrict__ bd4,
                const float* __restrict__ Wd5, const float* __restrict__ bd5,
                const float* __restrict__ Wd6, const float* __restrict__ bd6,
                float* __restrict__ m3, float* __restrict__ m4,
                float* __restrict__ out)
{
    __shared__ float v0[768];     // layer input
    __shared__ float v1[96];      // L1 output
    __shared__ float red[256];
    const int tid = threadIdx.x, b = blockIdx.x;

    // ---- L1: 24 -> 96, redundant per block ----
    if (tid < 24) v0[tid] = g[tid];          // g from previous dispatch: coherent
    __syncthreads();
    if (tid < 96) {
        float a = bd1[tid];
        #pragma unroll
        for (int i = 0; i < 24; i++) a = fmaf(v0[i], Wd1[i * 96 + tid], a);
        v1[tid] = fmaxf(a, 0.f);
    }
    __syncthreads();

    // ---- L2: 96 -> 256, redundant per block (one output per thread) ----
    {
        float a = bd2[tid];
        #pragma unroll
        for (int i = 0; i < 96; i++) a = fmaf(v1[i], Wd2[i * 256 + tid], a);
        red[tid] = fmaxf(a, 0.f);
    }
    __syncthreads();
    v0[tid] = red[tid];                       // L2 output -> v0[0..255]
    __syncthreads();

    // ---- L3: 256 -> 768, partitioned (48 outputs/block; 4 kg x K=64) ----
    if (tid < 192) {
        const int o = b * 48 + (tid % 48), kg = tid / 48;
        float a = 0.f;
        #pragma unroll 8
        for (int i = kg * 64; i < kg * 64 + 64; i++)
            a = fmaf(v0[i], Wd3[(size_t)i * 768 + o], a);
        red[tid] = a;
    }
    __syncthreads();
    if (tid < 48) {
        float s = bd3[b * 48 + tid] + red[tid] + red[48 + tid] + red[96 + tid] + red[144 + tid];
        gstore(&m3[b * 48 + tid], fmaxf(s, 0.f));
    }
    mbarrier(ctr, 1 * NBM, true);

    // ---- L4: 768 -> 512, partitioned (32 outputs/block; 8 kg x K=96) ----
    for (int i = tid; i < 768; i += 256) v0[i] = gload(&m3[i]);
    __syncthreads();
    {
        const int o = b * 32 + (tid & 31), kg = tid >> 5;
        float a = 0.f;
        #pragma unroll 8
        for (int i = kg * 96; i < kg * 96 + 96; i++)
            a = fmaf(v0[i], Wd4[(size_t)i * 512 + o], a);
        red[tid] = a;
    }
    __syncthreads();
    if (tid < 32) {
        float s = bd4[b * 32 + tid];
        #pragma unroll
        for (int k = 0; k < 8; k++) s += red[k * 32 + tid];
        gstore(&m4[b * 32 + tid], fmaxf(s, 0.f));
    }
    mbarrier(ctr, 2 * NBM, b == 0);          // only block 0 must wait

    // ---- L5+L6 in block 0: 512 -> 64 -> 1 ----
    if (b == 0) {
        for (int i = tid; i < 512; i += 256) v0[i] = gload(&m4[i]);
        __syncthreads();
        {
            const int o = tid & 63, kg = tid >> 6;   // 4 kg x K=128
            float a = 0.f;
            #pragma unroll 8
            for (int i = kg * 128; i < kg * 128 + 128; i++)
                a = fmaf(v0[i], Wd5[(size_t)i * 64 + o], a);
            red[tid] = a;
        }
        __syncthreads();
        if (tid < 64) {
            float s = bd5[tid] + red[tid] + red[64 + tid] + red[128 + tid] + red[192 + tid];
            float v = fmaxf(s, 0.f) * Wd6[tid];
            #pragma unroll
            for (int off = 32; off > 0; off >>= 1)
                v += __shfl_down(v, off, 64);
            if (tid == 0) out[0] = v + bd6[0];
        }
    }
}

// ---------------------------------------------------------------------------
extern "C" void kernel_launch(void* const* d_in, const int* in_sizes, int n_in,
                              void* d_out, int out_size, void* d_ws, size_t ws_size,
                              hipStream_t stream)
{
    const float* x     = (const float*)d_in[0];
    const int*   eidx  = (const int*)  d_in[1];
    const float* e     = (const float*)d_in[2];
    const float* We1   = (const float*)d_in[3];  const float* be1 = (const float*)d_in[4];
    const float* root1 = (const float*)d_in[5];  const float* b1  = (const float*)d_in[6];
    const float* We2   = (const float*)d_in[7];  const float* be2 = (const float*)d_in[8];
    const float* root2 = (const float*)d_in[9];  const float* b2  = (const float*)d_in[10];
    const float* We3   = (const float*)d_in[11]; const float* be3 = (const float*)d_in[12];
    const float* root3 = (const float*)d_in[13]; const float* b3  = (const float*)d_in[14];
    const float* Wd1 = (const float*)d_in[15]; const float* bd1 = (const float*)d_in[16];
    const float* Wd2 = (const float*)d_in[17]; const float* bd2 = (const float*)d_in[18];
    const float* Wd3 = (const float*)d_in[19]; const float* bd3 = (const float*)d_in[20];
    const float* Wd4 = (const float*)d_in[21]; const float* bd4 = (const float*)d_in[22];
    const float* Wd5 = (const float*)d_in[23]; const float* bd5 = (const float*)d_in[24];
    const float* Wd6 = (const float*)d_in[25]; const float* bd6 = (const float*)d_in[26];

    // ---- workspace layout (4-byte units) ----
    int*   wi     = (int*)d_ws;
    float* wf     = (float*)d_ws;
    int*   cnt_s  = wi;                        //       0 ..   20000
    float* g      = wf + 20000;                //   24
    int*   mctr   = wi + 20032;                //   own 64B line
    float* m3     = wf + 20064;                //   768
    float* m4     = m3 + 768;                  //   512  (ends 21344)
    float* hagg1  = wf + 21344;                //   20000*40 = 800,000 -> 821,344
    float* hagg2  = wf + 821344;               //   20000*24 = 480,000 -> 1,301,344
    float* hagg3  = wf + 1301344;              //   480,000 -> 1,781,344
    int*   se_eid = wi + 1781344;              //   20000*32 = 640,000 -> 2,421,344
    int*   se_tgt = wi + 2421344;              //   640,000 -> 3,061,344
    float* Pa     = wf + 3061344;              //   20000*400 = 8,000,000 -> 11,061,344
    float* Pb     = wf + 11061344;             //   20000*240 = 4,800,000 -> 15,861,344
    // total ~15.9M floats ~= 63.4 MB

    // D1: zero cnt_s + g + mctr + m3/m4 + hagg1/2/3 (contiguous prefix)
    hipMemsetAsync(d_ws, 0, (size_t)1781344 * sizeof(float), stream);

    // D2: src-bucket edges + nodeP layer 1 (x -> Pa, width 400)
    fill_nodeP1_kernel<<<1250, 256, 0, stream>>>(eidx, x, We1, be1, root1, b1,
                                                 cnt_s, se_eid, se_tgt, Pa);

    // L1 aggregate: push msgs from Pa into hagg1 (40-wide)
    push_kernel<40, 400, 64><<<NN / 4, 256, 0, stream>>>(Pa, cnt_s, se_eid, se_tgt, e, hagg1);

    // h1 = relu(hagg1 + Pa seg9); nodeP L2 -> Pb (width 240)
    hgemm_kernel<40, 24><<<625, 256, 0, stream>>>(hagg1, Pa, We2, be2, root2, b2, Pb);

    // L2 aggregate: push from Pb into hagg2 (24-wide)
    push_kernel<24, 240, 32><<<NN / 8, 256, 0, stream>>>(Pb, cnt_s, se_eid, se_tgt, e, hagg2);

    // h2 = relu(hagg2 + Pb seg9); nodeP L3 -> Pa region (width 240)
    hgemm_kernel<24, 24><<<625, 256, 0, stream>>>(hagg2, Pb, We3, be3, root3, b3, Pa);

    // L3 aggregate: push from Pa(240-wide) into hagg3
    push_kernel<24, 240, 32><<<NN / 8, 256, 0, stream>>>(Pa, cnt_s, se_eid, se_tgt, e, hagg3);

    // g = colsum(relu(hagg3 + Pa seg9))
    colsum_kernel<<<128, 256, 0, stream>>>(hagg3, Pa, g);

    // D6: MLP head (16 blocks, 2 internal barriers)
    mlp_kernel<<<NBM, 256, 0, stream>>>(g, mctr,
                                        Wd1, bd1, Wd2, bd2, Wd3, bd3,
                                        Wd4, bd4, Wd5, bd5, Wd6, bd6,
                                        m3, m4, (float*)d_out);
}